// Round 1
// baseline (144.384 us; speedup 1.0000x reference)
//
#include <hip/hip_runtime.h>
#include <hip/hip_bf16.h>

#define NN 4096
#define IN_F 128
#define HEADS 4
#define OUT_F 64
#define C_TOT 256
#define ALPHA 0.2f
#define NEG_FILL -9000000000000000.0f

typedef float f32x4 __attribute__((ext_vector_type(4)));
typedef __bf16 bf16x8 __attribute__((ext_vector_type(8)));

__device__ __forceinline__ unsigned short f2bf(float x) {
    unsigned int u = __float_as_uint(x);
    u += 0x7FFFu + ((u >> 16) & 1u);
    return (unsigned short)(u >> 16);
}

// ---------------------------------------------------------------------------
// Kernel 1: Wh = h @ W  (f32), write WhT (bf16, [256][4096]), left/right per head
// 256 blocks x 256 threads, 16 rows per block.
// ---------------------------------------------------------------------------
__global__ __launch_bounds__(256) void k_prep(
    const float* __restrict__ hmat,   // [4096][128]
    const float* __restrict__ W,      // [128][256]
    const float* __restrict__ a,      // [128]
    unsigned short* __restrict__ WhT, // [256][4096] bf16
    float* __restrict__ leftT,        // [4][4096]
    float* __restrict__ rightT,       // [4][4096]
    float* __restrict__ right4)       // [4096][4]
{
    __shared__ float hT[16 * 128];
    const int tid = threadIdx.x;
    const int rowbase = blockIdx.x * 16;

    for (int i = tid; i < 16 * 128; i += 256)
        hT[i] = hmat[(size_t)rowbase * IN_F + i];
    __syncthreads();

    const int c = tid; // output column 0..255
    float acc[16];
#pragma unroll
    for (int r = 0; r < 16; ++r) acc[r] = 0.f;

    for (int k4 = 0; k4 < 32; ++k4) {
        const float w0 = W[(k4 * 4 + 0) * C_TOT + c];
        const float w1 = W[(k4 * 4 + 1) * C_TOT + c];
        const float w2 = W[(k4 * 4 + 2) * C_TOT + c];
        const float w3 = W[(k4 * 4 + 3) * C_TOT + c];
#pragma unroll
        for (int r = 0; r < 16; ++r) {
            const float4 hv = *reinterpret_cast<const float4*>(&hT[r * 128 + k4 * 4]);
            acc[r] = fmaf(hv.x, w0, fmaf(hv.y, w1, fmaf(hv.z, w2, fmaf(hv.w, w3, acc[r]))));
        }
    }

#pragma unroll
    for (int r = 0; r < 16; ++r)
        WhT[(size_t)c * NN + rowbase + r] = f2bf(acc[r]);

    // left/right: wave = head, lane = feature
    const int hd = tid >> 6;
    const int f  = tid & 63;
    const float aL = a[f];
    const float aR = a[OUT_F + f];
#pragma unroll
    for (int r = 0; r < 16; ++r) {
        float lv = acc[r] * aL;
        float rv = acc[r] * aR;
#pragma unroll
        for (int s = 1; s < 64; s <<= 1) {
            lv += __shfl_xor(lv, s, 64);
            rv += __shfl_xor(rv, s, 64);
        }
        if (f == 0) {
            leftT [hd * NN + rowbase + r] = lv;
            rightT[hd * NN + rowbase + r] = rv;
            right4[(size_t)(rowbase + r) * 4 + hd] = rv;
        }
    }
}

// ---------------------------------------------------------------------------
// Kernel 2: per-row, per-head max of right[j] over neighbors -> softmax max m.
// One wave per row; 1024 blocks x 256 threads.
// ---------------------------------------------------------------------------
__global__ __launch_bounds__(256) void k_rowmax(
    const int* __restrict__ adj,      // [4096][4096]
    const float* __restrict__ right4, // [4096][4]
    const float* __restrict__ leftT,  // [4][4096]
    float* __restrict__ mT)           // [4][4096]
{
    const int wv = threadIdx.x >> 6;
    const int lane = threadIdx.x & 63;
    const int row = blockIdx.x * 4 + wv;

    const int4* arow = reinterpret_cast<const int4*>(adj + (size_t)row * NN);
    const float4* r4 = reinterpret_cast<const float4*>(right4);

    float m0 = -INFINITY, m1 = -INFINITY, m2 = -INFINITY, m3 = -INFINITY;
    for (int it = 0; it < 16; ++it) {
        const int idx = it * 64 + lane;
        const int4 av = arow[idx];
        const int jb = idx * 4;
        const float4 v0 = r4[jb + 0];
        const float4 v1 = r4[jb + 1];
        const float4 v2 = r4[jb + 2];
        const float4 v3 = r4[jb + 3];
        if (av.x > 0) { m0 = fmaxf(m0, v0.x); m1 = fmaxf(m1, v0.y); m2 = fmaxf(m2, v0.z); m3 = fmaxf(m3, v0.w); }
        if (av.y > 0) { m0 = fmaxf(m0, v1.x); m1 = fmaxf(m1, v1.y); m2 = fmaxf(m2, v1.z); m3 = fmaxf(m3, v1.w); }
        if (av.z > 0) { m0 = fmaxf(m0, v2.x); m1 = fmaxf(m1, v2.y); m2 = fmaxf(m2, v2.z); m3 = fmaxf(m3, v2.w); }
        if (av.w > 0) { m0 = fmaxf(m0, v3.x); m1 = fmaxf(m1, v3.y); m2 = fmaxf(m2, v3.z); m3 = fmaxf(m3, v3.w); }
    }
#pragma unroll
    for (int s = 1; s < 64; s <<= 1) {
        m0 = fmaxf(m0, __shfl_xor(m0, s, 64));
        m1 = fmaxf(m1, __shfl_xor(m1, s, 64));
        m2 = fmaxf(m2, __shfl_xor(m2, s, 64));
        m3 = fmaxf(m3, __shfl_xor(m3, s, 64));
    }
    if (lane == 0) {
        float mm[4] = { m0, m1, m2, m3 };
#pragma unroll
        for (int hd = 0; hd < 4; ++hd) {
            const float m = mm[hd];
            if (m == -INFINITY) {
                mT[hd * NN + row] = NEG_FILL; // no neighbors: all entries NEG_FILL
            } else {
                float e = leftT[hd * NN + row] + m;
                e = (e >= 0.f) ? e : ALPHA * e;
                mT[hd * NN + row] = e;
            }
        }
    }
}

// ---------------------------------------------------------------------------
// Kernel 3: attention + PV via MFMA. 256 blocks x 512 threads.
// Block = 16 query rows; wave (0..7) = (head 0..3) x (j-half 0..1).
// Per 32-wide j tile: lane builds 8 attn weights directly in A-fragment slots,
// 4x mfma_f32_16x16x32_bf16 against WhT rows (B fragment), f32 denominator.
// ---------------------------------------------------------------------------
__global__ __launch_bounds__(512) void k_attn(
    const int* __restrict__ adj,
    const unsigned short* __restrict__ WhT,
    const float* __restrict__ leftT,
    const float* __restrict__ rightT,
    const float* __restrict__ mT,
    const float* __restrict__ bias,
    float* __restrict__ out)
{
    __shared__ float comb[4][64][17];

    const int tid  = threadIdx.x;
    const int lane = tid & 63;
    const int wv   = tid >> 6;   // 0..7
    const int hd   = wv & 3;     // head
    const int jh   = wv >> 2;    // j half
    const int rowbase = blockIdx.x * 16;
    const int m  = lane & 15;    // A row within tile / B column
    const int kg = lane >> 4;    // k-octet group

    const float lf   = leftT[hd * NN + rowbase + m];
    const float mrow = mT  [hd * NN + rowbase + m];
    const float allm = (mrow < -1.0e15f) ? 1.0f : 0.0f;

    f32x4 acc[4];
#pragma unroll
    for (int q = 0; q < 4; ++q) acc[q] = (f32x4){0.f, 0.f, 0.f, 0.f};
    float lpart = 0.f;

    const size_t adjbase = (size_t)(rowbase + m) * NN;
    const int jstart = jh * 2048;
    const unsigned short* bp[4];
#pragma unroll
    for (int q = 0; q < 4; ++q)
        bp[q] = WhT + (size_t)(hd * 64 + q * 16 + m) * NN;
    const float* rrow = rightT + hd * NN;

    for (int t = 0; t < 64; ++t) {
        const int j0 = jstart + t * 32;
        const int jk = j0 + kg * 8;

        const int4 a0 = *reinterpret_cast<const int4*>(adj + adjbase + jk);
        const int4 a1 = *reinterpret_cast<const int4*>(adj + adjbase + jk + 4);
        const float4 r0 = *reinterpret_cast<const float4*>(rrow + jk);
        const float4 r1 = *reinterpret_cast<const float4*>(rrow + jk + 4);

        union { unsigned short u[8]; bf16x8 v; } A;
        const float rv[8] = { r0.x, r0.y, r0.z, r0.w, r1.x, r1.y, r1.z, r1.w };
        const int   ad[8] = { a0.x, a0.y, a0.z, a0.w, a1.x, a1.y, a1.z, a1.w };
#pragma unroll
        for (int i = 0; i < 8; ++i) {
            float e = lf + rv[i];
            e = (e >= 0.f) ? e : ALPHA * e;
            const float ex = __expf(e - mrow);
            const float w = (ad[i] > 0) ? ex : allm;
            const unsigned short us = f2bf(w);
            A.u[i] = us;
            lpart += __uint_as_float((unsigned)us << 16);
        }

#pragma unroll
        for (int q = 0; q < 4; ++q) {
            const bf16x8 b = *reinterpret_cast<const bf16x8*>(bp[q] + jk);
            acc[q] = __builtin_amdgcn_mfma_f32_16x16x32_bf16(A.v, b, acc[q], 0, 0, 0);
        }
    }

    if (jh == 1) {
#pragma unroll
        for (int q = 0; q < 4; ++q)
#pragma unroll
            for (int i = 0; i < 4; ++i)
                comb[hd][lane][q * 4 + i] = acc[q][i];
        comb[hd][lane][16] = lpart;
    }
    __syncthreads();
    if (jh == 0) {
#pragma unroll
        for (int q = 0; q < 4; ++q)
#pragma unroll
            for (int i = 0; i < 4; ++i)
                acc[q][i] += comb[hd][lane][q * 4 + i];
        lpart += comb[hd][lane][16];

        float lsum = lpart;
        lsum += __shfl_xor(lsum, 16, 64);
        lsum += __shfl_xor(lsum, 32, 64); // every lane: full denom for row (lane&15)

#pragma unroll
        for (int q = 0; q < 4; ++q) {
#pragma unroll
            for (int i = 0; i < 4; ++i) {
                const int r = kg * 4 + i;
                const float lr = __shfl(lsum, r, 64);
                const int col = hd * 64 + q * 16 + m;
                out[(size_t)(rowbase + r) * C_TOT + col] = acc[q][i] / lr + bias[col];
            }
        }
    }
}

extern "C" void kernel_launch(void* const* d_in, const int* in_sizes, int n_in,
                              void* d_out, int out_size, void* d_ws, size_t ws_size,
                              hipStream_t stream) {
    const float* hmat = (const float*)d_in[0];
    const int*   adj  = (const int*)d_in[1];
    const float* W    = (const float*)d_in[2];
    const float* a    = (const float*)d_in[3];
    const float* bias = (const float*)d_in[4];
    float* out = (float*)d_out;

    char* ws = (char*)d_ws;
    unsigned short* WhT = (unsigned short*)ws;                    // 2 MiB
    float* leftT  = (float*)(ws + (2u << 20));                    // 64 KiB
    float* rightT = (float*)(ws + (2u << 20) + 64 * 1024);        // 64 KiB
    float* right4 = (float*)(ws + (2u << 20) + 128 * 1024);       // 64 KiB
    float* mT     = (float*)(ws + (2u << 20) + 192 * 1024);       // 64 KiB

    hipLaunchKernelGGL(k_prep,   dim3(256),  dim3(256), 0, stream,
                       hmat, W, a, WhT, leftT, rightT, right4);
    hipLaunchKernelGGL(k_rowmax, dim3(1024), dim3(256), 0, stream,
                       adj, right4, leftT, mT);
    hipLaunchKernelGGL(k_attn,   dim3(256),  dim3(512), 0, stream,
                       adj, WhT, leftT, rightT, mT, bias, out);
}

// Round 3
// 117.217 us; speedup vs baseline: 1.2318x; 1.2318x over previous
//
#include <hip/hip_runtime.h>
#include <hip/hip_bf16.h>

#define NN 4096
#define IN_F 128
#define HEADS 4
#define OUT_F 64
#define C_TOT 256
#define ALPHA 0.2f

typedef float f32x4 __attribute__((ext_vector_type(4)));
typedef __bf16 bf16x8 __attribute__((ext_vector_type(8)));

__device__ __forceinline__ unsigned fmap(float f) {
    unsigned u = __float_as_uint(f);
    return (u >> 31) ? ~u : (u | 0x80000000u);
}
__device__ __forceinline__ float funmap(unsigned u) {
    return (u >> 31) ? __uint_as_float(u & 0x7FFFFFFFu) : __uint_as_float(~u);
}
__device__ __forceinline__ unsigned short bfbits(float x) {
    union { __bf16 b; unsigned short u; } t;
    t.b = (__bf16)x;
    return t.u;
}

// ---------------------------------------------------------------------------
// K0: WT bf16 [256][128], u = per-head W@a ([128][8]: L0..3,R0..3), zero Rmax.
// Grid 32 x 256.
// ---------------------------------------------------------------------------
__global__ __launch_bounds__(256) void k_misc(
    const float* __restrict__ W,      // [128][256]
    const float* __restrict__ a,      // [128]
    unsigned short* __restrict__ WTbf,// [256][128] bf16
    float* __restrict__ uLR,          // [128][8]
    unsigned int* __restrict__ Rmax)  // [4]
{
    const int b = blockIdx.x, tid = threadIdx.x;
    const int c = b * 8 + (tid & 7);
#pragma unroll
    for (int pass = 0; pass < 4; ++pass) {
        const int k = pass * 32 + (tid >> 3);
        WTbf[(size_t)c * IN_F + k] = bfbits(W[k * C_TOT + c]);
    }
    if (b == 0) {
        if (tid < 4) Rmax[tid] = 0u;
        for (int o = tid; o < 1024; o += 256) {
            const int k = o >> 3, j = o & 7;
            const int hd = j & 3, side = j >> 2;
            float s = 0.f;
            for (int f = 0; f < OUT_F; ++f)
                s = fmaf(W[k * C_TOT + hd * OUT_F + f], a[side * OUT_F + f], s);
            uLR[k * 8 + side * 4 + hd] = s;
        }
    }
}

// ---------------------------------------------------------------------------
// K1: Wh via MFMA (bf16) -> WhT [256][4096]; exact f32 left/right via u;
// global per-head right-max via atomic. Grid 256 x 256 (16 rows/block).
// ---------------------------------------------------------------------------
__global__ __launch_bounds__(256) void k_prep(
    const float* __restrict__ hmat,   // [4096][128]
    const unsigned short* __restrict__ WTbf,
    const float* __restrict__ uLR,
    unsigned short* __restrict__ WhT, // [256][4096]
    float* __restrict__ leftT,        // [4][4096]
    float* __restrict__ rightT,       // [4][4096]
    unsigned int* __restrict__ Rmax)
{
    __shared__ float hs[16][132];
    __shared__ float us[128][8];
    const int tid = threadIdx.x;
    const int rowbase = blockIdx.x * 16;

    ((float4*)us)[tid] = ((const float4*)uLR)[tid];
#pragma unroll
    for (int p = 0; p < 8; ++p) {
        const int idx = p * 256 + tid;
        hs[idx >> 7][idx & 127] = hmat[(size_t)rowbase * IN_F + idx];
    }
    __syncthreads();

    const int lane = tid & 63, wv = tid >> 6;
    const int m16 = lane & 15, kg = lane >> 4;

    if (wv == 0) {
        const int row = lane >> 2, hd = lane & 3;
        float aL = 0.f, aR = 0.f;
#pragma unroll
        for (int k = 0; k < 128; k += 4) {
            const float4 hv = *(const float4*)&hs[row][k];
            aL = fmaf(hv.x, us[k][hd],     fmaf(hv.y, us[k+1][hd],     fmaf(hv.z, us[k+2][hd],     fmaf(hv.w, us[k+3][hd],     aL))));
            aR = fmaf(hv.x, us[k][hd+4],   fmaf(hv.y, us[k+1][hd+4],   fmaf(hv.z, us[k+2][hd+4],   fmaf(hv.w, us[k+3][hd+4],   aR))));
        }
        leftT [hd * NN + rowbase + row] = aL;
        rightT[hd * NN + rowbase + row] = aR;
        float mx = aR;
#pragma unroll
        for (int s = 4; s < 64; s <<= 1) mx = fmaxf(mx, __shfl_xor(mx, s, 64));
        if (lane < 4) atomicMax(&Rmax[hd], fmap(mx));
    }

    // A fragments from LDS (bf16 convert)
    bf16x8 afr[4];
#pragma unroll
    for (int ks = 0; ks < 4; ++ks) {
        const float4 lo = *(const float4*)&hs[m16][ks * 32 + kg * 8];
        const float4 hi = *(const float4*)&hs[m16][ks * 32 + kg * 8 + 4];
        bf16x8 v;
        v[0] = (__bf16)lo.x; v[1] = (__bf16)lo.y; v[2] = (__bf16)lo.z; v[3] = (__bf16)lo.w;
        v[4] = (__bf16)hi.x; v[5] = (__bf16)hi.y; v[6] = (__bf16)hi.z; v[7] = (__bf16)hi.w;
        afr[ks] = v;
    }

#pragma unroll
    for (int nt0 = 0; nt0 < 4; ++nt0) {
        const int col = (wv * 4 + nt0) * 16 + m16;
        f32x4 acc = (f32x4){0.f, 0.f, 0.f, 0.f};
#pragma unroll
        for (int ks = 0; ks < 4; ++ks) {
            union { uint4 u; bf16x8 v; } B;
            B.u = *(const uint4*)(WTbf + (size_t)col * IN_F + ks * 32 + kg * 8);
            acc = __builtin_amdgcn_mfma_f32_16x16x32_bf16(afr[ks], B.v, acc, 0, 0, 0);
        }
#pragma unroll
        for (int i = 0; i < 4; ++i)
            WhT[(size_t)col * NN + rowbase + kg * 4 + i] = bfbits(acc[i]);
    }
}

// ---------------------------------------------------------------------------
// K2: attention + PV. Grid 256 x 1024. Block = 16 rows; 16 waves =
// 4 heads x 4 j-quarters (1024 j each = 32 tiles of 32, reg double-buffer).
// ---------------------------------------------------------------------------
__global__ __launch_bounds__(1024, 4) void k_attn(
    const int* __restrict__ adj,
    const unsigned short* __restrict__ WhT,
    const float* __restrict__ leftT,
    const float* __restrict__ rightT,
    const unsigned int* __restrict__ Rmax,
    const float* __restrict__ bias,
    float* __restrict__ out)
{
    __shared__ float comb[3][4][64][17];

    const int tid = threadIdx.x;
    const int lane = tid & 63;
    const int wv = tid >> 6;      // 0..15
    const int hd = wv & 3;
    const int jq = wv >> 2;       // 0..3
    const int rowbase = blockIdx.x * 16;
    const int m = lane & 15;
    const int kg = lane >> 4;

    const float lf = leftT[hd * NN + rowbase + m];
    const float rmx = funmap(Rmax[hd]);
    float mrow = lf + rmx;
    mrow = fmaxf(mrow, ALPHA * mrow);   // LeakyReLU of the max -> softmax shift

    f32x4 acc[4];
#pragma unroll
    for (int q = 0; q < 4; ++q) acc[q] = (f32x4){0.f, 0.f, 0.f, 0.f};
    float lpart = 0.f;

    const int jo = jq * 1024 + kg * 8;
    const int* __restrict__ ap = adj + (size_t)(rowbase + m) * NN + jo;
    const float* __restrict__ rp = rightT + hd * NN + jo;
    const unsigned short* __restrict__ bp0 = WhT + (size_t)(hd * 64 +  0 + m) * NN + jo;
    const unsigned short* __restrict__ bp1 = WhT + (size_t)(hd * 64 + 16 + m) * NN + jo;
    const unsigned short* __restrict__ bp2 = WhT + (size_t)(hd * 64 + 32 + m) * NN + jo;
    const unsigned short* __restrict__ bp3 = WhT + (size_t)(hd * 64 + 48 + m) * NN + jo;

    union I8 { int4 i4[2]; int s[8]; };
    union F8 { float4 f4[2]; float s[8]; };
    union B8 { uint4 u; bf16x8 v; };

    I8 ca; F8 cr; B8 cb0, cb1, cb2, cb3;
    ca.i4[0] = *(const int4*)ap;        ca.i4[1] = *(const int4*)(ap + 4);
    cr.f4[0] = *(const float4*)rp;      cr.f4[1] = *(const float4*)(rp + 4);
    cb0.u = *(const uint4*)bp0;  cb1.u = *(const uint4*)bp1;
    cb2.u = *(const uint4*)bp2;  cb3.u = *(const uint4*)bp3;

#pragma unroll 2
    for (int t = 0; t < 32; ++t) {
        I8 na; F8 nr; B8 nb0, nb1, nb2, nb3;
        if (t < 31) {
            const int off = (t + 1) * 32;
            na.i4[0] = *(const int4*)(ap + off);       na.i4[1] = *(const int4*)(ap + off + 4);
            nr.f4[0] = *(const float4*)(rp + off);     nr.f4[1] = *(const float4*)(rp + off + 4);
            nb0.u = *(const uint4*)(bp0 + off);  nb1.u = *(const uint4*)(bp1 + off);
            nb2.u = *(const uint4*)(bp2 + off);  nb3.u = *(const uint4*)(bp3 + off);
        }
        union { unsigned short us[8]; bf16x8 v; } A;
#pragma unroll
        for (int i = 0; i < 8; ++i) {
            float e = lf + cr.s[i];
            e = fmaxf(e, ALPHA * e);                  // LeakyReLU
            const float ex = __expf(e - mrow);
            const float w = (ca.s[i] > 0) ? ex : 0.f; // mask
            const unsigned short us = bfbits(w);
            A.us[i] = us;
            lpart += __uint_as_float((unsigned)us << 16); // rounded, matches numerator
        }
        acc[0] = __builtin_amdgcn_mfma_f32_16x16x32_bf16(A.v, cb0.v, acc[0], 0, 0, 0);
        acc[1] = __builtin_amdgcn_mfma_f32_16x16x32_bf16(A.v, cb1.v, acc[1], 0, 0, 0);
        acc[2] = __builtin_amdgcn_mfma_f32_16x16x32_bf16(A.v, cb2.v, acc[2], 0, 0, 0);
        acc[3] = __builtin_amdgcn_mfma_f32_16x16x32_bf16(A.v, cb3.v, acc[3], 0, 0, 0);
        ca = na; cr = nr;
        cb0 = nb0; cb1 = nb1; cb2 = nb2; cb3 = nb3;
    }

    if (jq > 0) {
#pragma unroll
        for (int q = 0; q < 4; ++q)
#pragma unroll
            for (int i = 0; i < 4; ++i)
                comb[jq - 1][hd][lane][q * 4 + i] = acc[q][i];
        comb[jq - 1][hd][lane][16] = lpart;
    }
    __syncthreads();
    if (jq == 0) {
#pragma unroll
        for (int p = 0; p < 3; ++p) {
#pragma unroll
            for (int q = 0; q < 4; ++q)
#pragma unroll
                for (int i = 0; i < 4; ++i)
                    acc[q][i] += comb[p][hd][lane][q * 4 + i];
            lpart += comb[p][hd][lane][16];
        }
        float lsum = lpart;
        lsum += __shfl_xor(lsum, 16, 64);
        lsum += __shfl_xor(lsum, 32, 64);   // full denom for row m on every lane

#pragma unroll
        for (int q = 0; q < 4; ++q) {
#pragma unroll
            for (int i = 0; i < 4; ++i) {
                const int r = kg * 4 + i;
                const float lr = __shfl(lsum, r, 64);
                const int col = hd * 64 + q * 16 + m;
                out[(size_t)(rowbase + r) * C_TOT + col] = acc[q][i] / lr + bias[col];
            }
        }
    }
}

extern "C" void kernel_launch(void* const* d_in, const int* in_sizes, int n_in,
                              void* d_out, int out_size, void* d_ws, size_t ws_size,
                              hipStream_t stream) {
    const float* hmat = (const float*)d_in[0];
    const int*   adj  = (const int*)d_in[1];
    const float* W    = (const float*)d_in[2];
    const float* a    = (const float*)d_in[3];
    const float* bias = (const float*)d_in[4];
    float* out = (float*)d_out;

    char* ws = (char*)d_ws;
    unsigned short* WhT  = (unsigned short*)ws;                      // 2 MiB
    float* leftT         = (float*)(ws + 2097152);                   // 64 KiB
    float* rightT        = (float*)(ws + 2097152 + 65536);           // 64 KiB
    unsigned short* WTbf = (unsigned short*)(ws + 2097152 + 131072); // 64 KiB
    float* uLR           = (float*)(ws + 2097152 + 196608);          // 4 KiB
    unsigned int* Rmax   = (unsigned int*)(ws + 2097152 + 200704);   // 16 B

    hipLaunchKernelGGL(k_misc, dim3(32),  dim3(256),  0, stream, W, a, WTbf, uLR, Rmax);
    hipLaunchKernelGGL(k_prep, dim3(256), dim3(256),  0, stream, hmat, WTbf, uLR, WhT, leftT, rightT, Rmax);
    hipLaunchKernelGGL(k_attn, dim3(256), dim3(1024), 0, stream, adj, WhT, leftT, rightT, Rmax, bias, out);
}

// Round 4
// 102.174 us; speedup vs baseline: 1.4131x; 1.1472x over previous
//
#include <hip/hip_runtime.h>
#include <hip/hip_bf16.h>

#define NN 4096
#define IN_F 128
#define OUT_F 64
#define C_TOT 256
#define ALPHA 0.2f
#define LOG2E 1.4426950408889634f

typedef float f32x4 __attribute__((ext_vector_type(4)));
typedef float f32x2 __attribute__((ext_vector_type(2)));
typedef __bf16 bf16x8 __attribute__((ext_vector_type(8)));

__device__ __forceinline__ unsigned fmap(float f) {
    unsigned u = __float_as_uint(f);
    return (u >> 31) ? ~u : (u | 0x80000000u);
}
__device__ __forceinline__ float funmap(unsigned u) {
    return (u >> 31) ? __uint_as_float(u & 0x7FFFFFFFu) : __uint_as_float(~u);
}
__device__ __forceinline__ unsigned short bfbits(float x) {
    union { __bf16 b; unsigned short u; } t;
    t.b = (__bf16)x;
    return t.u;
}

// ---------------------------------------------------------------------------
// K0: WT bf16 [256][128], u = per-head W@a ([128][8]), zero Rmax. Grid 32x256.
// ---------------------------------------------------------------------------
__global__ __launch_bounds__(256) void k_misc(
    const float* __restrict__ W, const float* __restrict__ a,
    unsigned short* __restrict__ WTbf, float* __restrict__ uLR,
    unsigned int* __restrict__ Rmax)
{
    const int b = blockIdx.x, tid = threadIdx.x;
    const int c = b * 8 + (tid & 7);
#pragma unroll
    for (int pass = 0; pass < 4; ++pass) {
        const int k = pass * 32 + (tid >> 3);
        WTbf[(size_t)c * IN_F + k] = bfbits(W[k * C_TOT + c]);
    }
    if (b == 0) {
        if (tid < 4) Rmax[tid] = 0u;
        for (int o = tid; o < 1024; o += 256) {
            const int k = o >> 3, j = o & 7;
            const int hd = j & 3, side = j >> 2;
            float s = 0.f;
            for (int f = 0; f < OUT_F; ++f)
                s = fmaf(W[k * C_TOT + hd * OUT_F + f], a[side * OUT_F + f], s);
            uLR[k * 8 + side * 4 + hd] = s;
        }
    }
}

// ---------------------------------------------------------------------------
// K1: adj (int32 0/1, 64MB) -> bitmask [4096][128 words] (2MB) via ballot.
// Grid 1024 x 256; wave = one row.
// ---------------------------------------------------------------------------
__global__ __launch_bounds__(256) void k_mask(
    const int* __restrict__ adj, unsigned* __restrict__ mask)
{
    const int lane = threadIdx.x & 63, wv = threadIdx.x >> 6;
    const int row = blockIdx.x * 4 + wv;
    const int* __restrict__ ar = adj + (size_t)row * NN;
    unsigned* __restrict__ mr = mask + (size_t)row * 128;
    for (int c = 0; c < 8; ++c) {
        const int j0 = c * 512;
        unsigned w = 0u;
#pragma unroll
        for (int k = 0; k < 8; ++k) {
            const unsigned long long bb = __ballot(ar[j0 + k * 64 + lane] > 0);
            const unsigned lo = (unsigned)bb, hi = (unsigned)(bb >> 32);
            if ((lane >> 1) == k) w = (lane & 1) ? hi : lo;
        }
        if (lane < 16) mr[(j0 >> 5) + lane] = w;
    }
}

// ---------------------------------------------------------------------------
// K2: Wh via MFMA -> WhT [256][4096] bf16; f32 left / right*LOG2E; Rmax atomic.
// Grid 256 x 256 (16 rows/block).
// ---------------------------------------------------------------------------
__global__ __launch_bounds__(256) void k_prep(
    const float* __restrict__ hmat, const unsigned short* __restrict__ WTbf,
    const float* __restrict__ uLR, unsigned short* __restrict__ WhT,
    float* __restrict__ leftT, float* __restrict__ rightT,
    unsigned int* __restrict__ Rmax)
{
    __shared__ float hs[16][132];
    __shared__ float us[128][8];
    const int tid = threadIdx.x;
    const int rowbase = blockIdx.x * 16;

    ((float4*)us)[tid] = ((const float4*)uLR)[tid];
#pragma unroll
    for (int p = 0; p < 8; ++p) {
        const int idx = p * 256 + tid;
        hs[idx >> 7][idx & 127] = hmat[(size_t)rowbase * IN_F + idx];
    }
    __syncthreads();

    const int lane = tid & 63, wv = tid >> 6;
    const int m16 = lane & 15, kg = lane >> 4;

    if (wv == 0) {
        const int row = lane >> 2, hd = lane & 3;
        float aL = 0.f, aR = 0.f;
#pragma unroll
        for (int k = 0; k < 128; k += 4) {
            const float4 hv = *(const float4*)&hs[row][k];
            aL = fmaf(hv.x, us[k][hd],   fmaf(hv.y, us[k+1][hd],   fmaf(hv.z, us[k+2][hd],   fmaf(hv.w, us[k+3][hd],   aL))));
            aR = fmaf(hv.x, us[k][hd+4], fmaf(hv.y, us[k+1][hd+4], fmaf(hv.z, us[k+2][hd+4], fmaf(hv.w, us[k+3][hd+4], aR))));
        }
        leftT [hd * NN + rowbase + row] = aL;
        rightT[hd * NN + rowbase + row] = aR * LOG2E;
        float mx = aR;
#pragma unroll
        for (int s = 4; s < 64; s <<= 1) mx = fmaxf(mx, __shfl_xor(mx, s, 64));
        if (lane < 4) atomicMax(&Rmax[hd], fmap(mx));
    }

    bf16x8 afr[4];
#pragma unroll
    for (int ks = 0; ks < 4; ++ks) {
        const float4 lo = *(const float4*)&hs[m16][ks * 32 + kg * 8];
        const float4 hi = *(const float4*)&hs[m16][ks * 32 + kg * 8 + 4];
        bf16x8 v;
        v[0] = (__bf16)lo.x; v[1] = (__bf16)lo.y; v[2] = (__bf16)lo.z; v[3] = (__bf16)lo.w;
        v[4] = (__bf16)hi.x; v[5] = (__bf16)hi.y; v[6] = (__bf16)hi.z; v[7] = (__bf16)hi.w;
        afr[ks] = v;
    }

#pragma unroll
    for (int nt0 = 0; nt0 < 4; ++nt0) {
        const int col = (wv * 4 + nt0) * 16 + m16;
        f32x4 acc = (f32x4){0.f, 0.f, 0.f, 0.f};
#pragma unroll
        for (int ks = 0; ks < 4; ++ks) {
            union { uint4 u; bf16x8 v; } B;
            B.u = *(const uint4*)(WTbf + (size_t)col * IN_F + ks * 32 + kg * 8);
            acc = __builtin_amdgcn_mfma_f32_16x16x32_bf16(afr[ks], B.v, acc, 0, 0, 0);
        }
#pragma unroll
        for (int i = 0; i < 4; ++i)
            WhT[(size_t)col * NN + rowbase + kg * 4 + i] = bfbits(acc[i]);
    }
}

// ---------------------------------------------------------------------------
// K3: attention + PV. Grid 512 x 512. Block = 16 rows x 2 heads; wave =
// (jq 0..3, hd01 0..1), 1024 j per wave = 32 tiles of 32. Mask rows in LDS.
// Ping-pong register pipeline, unconditional prefetch (ws arrays padded).
// ---------------------------------------------------------------------------
__global__ __launch_bounds__(512, 4) void k_attn(
    const unsigned* __restrict__ mask,
    const unsigned short* __restrict__ WhT,
    const float* __restrict__ leftT,
    const float* __restrict__ rightT,   // pre-scaled by LOG2E
    const unsigned int* __restrict__ Rmax,
    const float* __restrict__ bias,
    float* __restrict__ out)
{
    __shared__ unsigned mask_lds[16 * 132];
    __shared__ float comb[3][2][64][17];

    const int tid = threadIdx.x;
    const int lane = tid & 63;
    const int wv = tid >> 6;          // 0..7
    const int hd01 = wv & 1;
    const int jq = wv >> 1;           // 0..3
    const int rowbase = (blockIdx.x >> 1) * 16;
    const int hd = ((blockIdx.x & 1) << 1) | hd01;
    const int m = lane & 15;
    const int kg = lane >> 4;
    const int sh = kg * 8;

    {   // stage 16 mask rows (8KB) into LDS, row stride 132 words
        const uint4 v = *reinterpret_cast<const uint4*>(mask + (size_t)rowbase * 128 + tid * 4);
        *reinterpret_cast<uint4*>(&mask_lds[(tid >> 5) * 132 + (tid & 31) * 4]) = v;
    }

    const float lf = leftT[hd * NN + rowbase + m];
    const float rmx = funmap(Rmax[hd]);
    const float x = lf + rmx;
    const float m0 = fmaxf(x, ALPHA * x);        // softmax shift (upper bound)
    const float mp0 = m0 * LOG2E;
    const float lf2 = fmaf(lf, LOG2E, -mp0);
    const float qc = -0.8f * mp0;

    __syncthreads();

    const float* __restrict__ rp = rightT + hd * NN + jq * 1024 + sh;
    const unsigned short* __restrict__ bp0 = WhT + (size_t)(hd * 64 +  0 + m) * NN + jq * 1024 + sh;
    const unsigned short* __restrict__ bp1 = WhT + (size_t)(hd * 64 + 16 + m) * NN + jq * 1024 + sh;
    const unsigned short* __restrict__ bp2 = WhT + (size_t)(hd * 64 + 32 + m) * NN + jq * 1024 + sh;
    const unsigned short* __restrict__ bp3 = WhT + (size_t)(hd * 64 + 48 + m) * NN + jq * 1024 + sh;
    const uint2* __restrict__ mwp = reinterpret_cast<const uint2*>(&mask_lds[m * 132 + jq * 32]);

    union F8 { f32x2 h[4]; float4 f4[2]; };
    union B8 { uint4 u; bf16x8 v; };

    f32x4 acc0 = (f32x4){0,0,0,0}, acc1 = acc0, acc2 = acc0, acc3 = acc0;
    f32x2 lp = (f32x2){0.f, 0.f};

#define LOADR(dst, off) { dst.f4[0] = *(const float4*)(rp + (off)); dst.f4[1] = *(const float4*)(rp + (off) + 4); }
#define LOADB(d0,d1,d2,d3, off) { d0.u = *(const uint4*)(bp0 + (off)); d1.u = *(const uint4*)(bp1 + (off)); \
                                  d2.u = *(const uint4*)(bp2 + (off)); d3.u = *(const uint4*)(bp3 + (off)); }
#define CONSUME(MW, R, B0,B1,B2,B3) {                                          \
    const unsigned aw = (MW) >> sh;                                            \
    union { __bf16 b[8]; bf16x8 v; } Af;                                       \
    _Pragma("unroll")                                                          \
    for (int e = 0; e < 4; ++e) {                                              \
        f32x2 pv = R.h[e] + lf2;                                               \
        f32x2 qv = pv * ALPHA + qc;                                            \
        float t0 = fmaxf(pv.x, qv.x), t1 = fmaxf(pv.y, qv.y);                  \
        float w0 = exp2f(t0), w1 = exp2f(t1);                                  \
        const unsigned mk0 = (unsigned)(((int)(aw << (31 - (2*e  )))) >> 31);  \
        const unsigned mk1 = (unsigned)(((int)(aw << (31 - (2*e+1)))) >> 31);  \
        w0 = __uint_as_float(__float_as_uint(w0) & mk0);                       \
        w1 = __uint_as_float(__float_as_uint(w1) & mk1);                       \
        lp += (f32x2){w0, w1};                                                 \
        Af.b[2*e] = (__bf16)w0; Af.b[2*e+1] = (__bf16)w1;                      \
    }                                                                          \
    acc0 = __builtin_amdgcn_mfma_f32_16x16x32_bf16(Af.v, B0.v, acc0, 0, 0, 0); \
    acc1 = __builtin_amdgcn_mfma_f32_16x16x32_bf16(Af.v, B1.v, acc1, 0, 0, 0); \
    acc2 = __builtin_amdgcn_mfma_f32_16x16x32_bf16(Af.v, B2.v, acc2, 0, 0, 0); \
    acc3 = __builtin_amdgcn_mfma_f32_16x16x32_bf16(Af.v, B3.v, acc3, 0, 0, 0); }

    F8 Ra, Rb; B8 Ba0, Ba1, Ba2, Ba3, Bb0, Bb1, Bb2, Bb3;
    uint2 mw = mwp[0];
    LOADR(Ra, 0); LOADB(Ba0, Ba1, Ba2, Ba3, 0);

    for (int pp = 0; pp < 16; ++pp) {
        const int off1 = pp * 64 + 32;
        const int off2 = pp * 64 + 64;
        const uint2 mwn = mwp[pp + 1];                 // in-LDS, OOB-safe
        LOADR(Rb, off1); LOADB(Bb0, Bb1, Bb2, Bb3, off1);
        CONSUME(mw.x, Ra, Ba0, Ba1, Ba2, Ba3);         // tile 2pp
        LOADR(Ra, off2); LOADB(Ba0, Ba1, Ba2, Ba3, off2);  // tile 2pp+2 (padded OOB-safe)
        CONSUME(mw.y, Rb, Bb0, Bb1, Bb2, Bb3);         // tile 2pp+1
        mw = mwn;
    }
#undef LOADR
#undef LOADB
#undef CONSUME

    float lpart = lp.x + lp.y;
    if (jq > 0) {
#pragma unroll
        for (int i = 0; i < 4; ++i) {
            comb[jq-1][hd01][lane][ 0+i] = acc0[i];
            comb[jq-1][hd01][lane][ 4+i] = acc1[i];
            comb[jq-1][hd01][lane][ 8+i] = acc2[i];
            comb[jq-1][hd01][lane][12+i] = acc3[i];
        }
        comb[jq-1][hd01][lane][16] = lpart;
    }
    __syncthreads();
    if (jq == 0) {
#pragma unroll
        for (int pt = 0; pt < 3; ++pt) {
#pragma unroll
            for (int i = 0; i < 4; ++i) {
                acc0[i] += comb[pt][hd01][lane][ 0+i];
                acc1[i] += comb[pt][hd01][lane][ 4+i];
                acc2[i] += comb[pt][hd01][lane][ 8+i];
                acc3[i] += comb[pt][hd01][lane][12+i];
            }
            lpart += comb[pt][hd01][lane][16];
        }
        float lsum = lpart;
        lsum += __shfl_xor(lsum, 16, 64);
        lsum += __shfl_xor(lsum, 32, 64);   // full row denominator on every lane

#pragma unroll
        for (int q = 0; q < 4; ++q) {
            const f32x4 A = (q == 0) ? acc0 : (q == 1) ? acc1 : (q == 2) ? acc2 : acc3;
            const int col = hd * 64 + q * 16 + m;
            const float bv = bias[col];
#pragma unroll
            for (int i = 0; i < 4; ++i) {
                const int r = kg * 4 + i;
                const float lr = __shfl(lsum, r, 64);
                out[(size_t)(rowbase + r) * C_TOT + col] = A[i] / lr + bv;
            }
        }
    }
}

extern "C" void kernel_launch(void* const* d_in, const int* in_sizes, int n_in,
                              void* d_out, int out_size, void* d_ws, size_t ws_size,
                              hipStream_t stream) {
    const float* hmat = (const float*)d_in[0];
    const int*   adj  = (const int*)d_in[1];
    const float* W    = (const float*)d_in[2];
    const float* a    = (const float*)d_in[3];
    const float* bias = (const float*)d_in[4];
    float* out = (float*)d_out;

    char* ws = (char*)d_ws;
    unsigned short* WhT  = (unsigned short*)(ws + 0x000000);  // 2MB (+pad)
    float* rightT        = (float*)(ws + 0x280000);           // 64KB (+pad)
    float* leftT         = (float*)(ws + 0x2A0000);           // 64KB
    unsigned short* WTbf = (unsigned short*)(ws + 0x2B0000);  // 64KB
    float* uLR           = (float*)(ws + 0x2C0000);           // 4KB
    unsigned int* Rmax   = (unsigned int*)(ws + 0x2C1000);    // 16B
    unsigned* mask       = (unsigned*)(ws + 0x300000);        // 2MB  (total 5MB)

    hipLaunchKernelGGL(k_misc, dim3(32),   dim3(256), 0, stream, W, a, WTbf, uLR, Rmax);
    hipLaunchKernelGGL(k_mask, dim3(1024), dim3(256), 0, stream, adj, mask);
    hipLaunchKernelGGL(k_prep, dim3(256),  dim3(256), 0, stream, hmat, WTbf, uLR, WhT, leftT, rightT, Rmax);
    hipLaunchKernelGGL(k_attn, dim3(512),  dim3(512), 0, stream, mask, WhT, leftT, rightT, Rmax, bias, out);
}

// Round 5
// 98.786 us; speedup vs baseline: 1.4616x; 1.0343x over previous
//
#include <hip/hip_runtime.h>
#include <hip/hip_bf16.h>

#define NN 4096
#define IN_F 128
#define OUT_F 64
#define C_TOT 256
#define ALPHA 0.2f
#define LOG2E 1.4426950408889634f

typedef float f32x4 __attribute__((ext_vector_type(4)));
typedef float f32x2 __attribute__((ext_vector_type(2)));
typedef __bf16 bf16x8 __attribute__((ext_vector_type(8)));

__device__ __forceinline__ unsigned fmap(float f) {
    unsigned u = __float_as_uint(f);
    return (u >> 31) ? ~u : (u | 0x80000000u);
}
__device__ __forceinline__ float funmap(unsigned u) {
    return (u >> 31) ? __uint_as_float(u & 0x7FFFFFFFu) : __uint_as_float(~u);
}
__device__ __forceinline__ unsigned short bfbits(float x) {
    union { __bf16 b; unsigned short u; } t;
    t.b = (__bf16)x;
    return t.u;
}
__device__ __forceinline__ void gl16(const void* g, void* l) {
    __builtin_amdgcn_global_load_lds((const __attribute__((address_space(1))) void*)g,
                                     (__attribute__((address_space(3))) void*)l, 16, 0, 0);
}
__device__ __forceinline__ void gl4(const void* g, void* l) {
    __builtin_amdgcn_global_load_lds((const __attribute__((address_space(1))) void*)g,
                                     (__attribute__((address_space(3))) void*)l, 4, 0, 0);
}

// ---------------------------------------------------------------------------
// K0: WT bf16 [256][128], u = per-head W@a ([128][8]), zero Rmax. Grid 32x256.
// ---------------------------------------------------------------------------
__global__ __launch_bounds__(256) void k_misc(
    const float* __restrict__ W, const float* __restrict__ a,
    unsigned short* __restrict__ WTbf, float* __restrict__ uLR,
    unsigned int* __restrict__ Rmax)
{
    const int b = blockIdx.x, tid = threadIdx.x;
    const int c = b * 8 + (tid & 7);
#pragma unroll
    for (int pass = 0; pass < 4; ++pass) {
        const int k = pass * 32 + (tid >> 3);
        WTbf[(size_t)c * IN_F + k] = bfbits(W[k * C_TOT + c]);
    }
    if (b == 0) {
        if (tid < 4) Rmax[tid] = 0u;
        for (int o = tid; o < 1024; o += 256) {
            const int k = o >> 3, j = o & 7;
            const int hd = j & 3, side = j >> 2;
            float s = 0.f;
            for (int f = 0; f < OUT_F; ++f)
                s = fmaf(W[k * C_TOT + hd * OUT_F + f], a[side * OUT_F + f], s);
            uLR[k * 8 + side * 4 + hd] = s;
        }
    }
}

// ---------------------------------------------------------------------------
// K1: adj (int32 0/1, 64MB) -> bitmask [4096][128 words] (2MB) via ballot.
// ---------------------------------------------------------------------------
__global__ __launch_bounds__(256) void k_mask(
    const int* __restrict__ adj, unsigned* __restrict__ mask)
{
    const int lane = threadIdx.x & 63, wv = threadIdx.x >> 6;
    const int row = blockIdx.x * 4 + wv;
    const int* __restrict__ ar = adj + (size_t)row * NN;
    unsigned* __restrict__ mr = mask + (size_t)row * 128;
    for (int c = 0; c < 8; ++c) {
        const int j0 = c * 512;
        unsigned w = 0u;
#pragma unroll
        for (int k = 0; k < 8; ++k) {
            const unsigned long long bb = __ballot(ar[j0 + k * 64 + lane] > 0);
            const unsigned lo = (unsigned)bb, hi = (unsigned)(bb >> 32);
            if ((lane >> 1) == k) w = (lane & 1) ? hi : lo;
        }
        if (lane < 16) mr[(j0 >> 5) + lane] = w;
    }
}

// ---------------------------------------------------------------------------
// K2: Wh via MFMA -> WhT [256][4096] bf16; f32 left / right*LOG2E; Rmax atomic.
// ---------------------------------------------------------------------------
__global__ __launch_bounds__(256) void k_prep(
    const float* __restrict__ hmat, const unsigned short* __restrict__ WTbf,
    const float* __restrict__ uLR, unsigned short* __restrict__ WhT,
    float* __restrict__ leftT, float* __restrict__ rightT,
    unsigned int* __restrict__ Rmax)
{
    __shared__ float hs[16][132];
    __shared__ float us[128][8];
    const int tid = threadIdx.x;
    const int rowbase = blockIdx.x * 16;

    ((float4*)us)[tid] = ((const float4*)uLR)[tid];
#pragma unroll
    for (int p = 0; p < 8; ++p) {
        const int idx = p * 256 + tid;
        hs[idx >> 7][idx & 127] = hmat[(size_t)rowbase * IN_F + idx];
    }
    __syncthreads();

    const int lane = tid & 63, wv = tid >> 6;
    const int m16 = lane & 15, kg = lane >> 4;

    if (wv == 0) {
        const int row = lane >> 2, hd = lane & 3;
        float aL = 0.f, aR = 0.f;
#pragma unroll
        for (int k = 0; k < 128; k += 4) {
            const float4 hv = *(const float4*)&hs[row][k];
            aL = fmaf(hv.x, us[k][hd],   fmaf(hv.y, us[k+1][hd],   fmaf(hv.z, us[k+2][hd],   fmaf(hv.w, us[k+3][hd],   aL))));
            aR = fmaf(hv.x, us[k][hd+4], fmaf(hv.y, us[k+1][hd+4], fmaf(hv.z, us[k+2][hd+4], fmaf(hv.w, us[k+3][hd+4], aR))));
        }
        leftT [hd * NN + rowbase + row] = aL;
        rightT[hd * NN + rowbase + row] = aR * LOG2E;
        float mx = aR;
#pragma unroll
        for (int s = 4; s < 64; s <<= 1) mx = fmaxf(mx, __shfl_xor(mx, s, 64));
        if (lane < 4) atomicMax(&Rmax[hd], fmap(mx));
    }

    bf16x8 afr[4];
#pragma unroll
    for (int ks = 0; ks < 4; ++ks) {
        const float4 lo = *(const float4*)&hs[m16][ks * 32 + kg * 8];
        const float4 hi = *(const float4*)&hs[m16][ks * 32 + kg * 8 + 4];
        bf16x8 v;
        v[0] = (__bf16)lo.x; v[1] = (__bf16)lo.y; v[2] = (__bf16)lo.z; v[3] = (__bf16)lo.w;
        v[4] = (__bf16)hi.x; v[5] = (__bf16)hi.y; v[6] = (__bf16)hi.z; v[7] = (__bf16)hi.w;
        afr[ks] = v;
    }

#pragma unroll
    for (int nt0 = 0; nt0 < 4; ++nt0) {
        const int col = (wv * 4 + nt0) * 16 + m16;
        f32x4 acc = (f32x4){0.f, 0.f, 0.f, 0.f};
#pragma unroll
        for (int ks = 0; ks < 4; ++ks) {
            union { uint4 u; bf16x8 v; } B;
            B.u = *(const uint4*)(WTbf + (size_t)col * IN_F + ks * 32 + kg * 8);
            acc = __builtin_amdgcn_mfma_f32_16x16x32_bf16(afr[ks], B.v, acc, 0, 0, 0);
        }
#pragma unroll
        for (int i = 0; i < 4; ++i)
            WhT[(size_t)col * NN + rowbase + kg * 4 + i] = bfbits(acc[i]);
    }
}

// ---------------------------------------------------------------------------
// K3: attention + PV, m97-style 2-phase global_load_lds pipeline.
// Grid 256 x 512. Block = 32 rows x 2 heads; 8 waves = (rowhalf, hd01, jhalf).
// j-tile 64, B panel (128 rows x 64 j bf16, 16KB) double-buffered in LDS with
// granule XOR swizzle (linear dest + swizzled SOURCE + swizzled read).
// ---------------------------------------------------------------------------
__global__ __launch_bounds__(512) void k_attn(
    const unsigned* __restrict__ mask,
    const unsigned short* __restrict__ WhT,
    const float* __restrict__ leftT,
    const float* __restrict__ rightT,   // pre-scaled by LOG2E
    const unsigned int* __restrict__ Rmax,
    const float* __restrict__ bias,
    float* __restrict__ out)
{
    __shared__ unsigned short Bb[2][128 * 64];  // 2 x 16KB
    __shared__ float rb[2][2][64];              // 2 x 512B
    __shared__ unsigned mask_lds[32 * 132];     // 16.5KB
    __shared__ float comb[4][64][17];           // 17.4KB

    const int tid = threadIdx.x;
    const int lane = tid & 63;
    const int wv = tid >> 6;          // 0..7
    const int hd01 = wv & 1;
    const int jhalf = (wv >> 1) & 1;
    const int rh = wv >> 2;
    const int rowbase = (blockIdx.x >> 1) * 32;
    const int hdbase = (blockIdx.x & 1) * 2;
    const int hd = hdbase + hd01;
    const int m = lane & 15;
    const int kg = lane >> 4;

    // stage 32 mask rows (16KB) into LDS, row stride 132 words
#pragma unroll
    for (int p = 0; p < 2; ++p) {
        const int i = p * 512 + tid;          // uint4 index 0..1023
        const uint4 v = *(const uint4*)(mask + (size_t)(rowbase + (i >> 5)) * 128 + (i & 31) * 4);
        *(uint4*)&mask_lds[(i >> 5) * 132 + (i & 31) * 4] = v;
    }

    // per-lane softmax constants
    const float lf = leftT[hd * NN + rowbase + rh * 16 + m];
    const float rmx = funmap(Rmax[hd]);
    const float x = lf + rmx;
    const float m0v = fmaxf(x, ALPHA * x);
    const float mp0 = m0v * LOG2E;
    const float lf2 = fmaf(lf, LOG2E, -mp0);
    const float qc = -0.8f * mp0;

    // staging geometry: wave wv covers LDS rows wv*8..wv*8+7 and +64 (2 issues)
    const int lrow = lane >> 3;                 // 0..7 row within 8-row stripe
    const int sgr = (lane & 7) ^ lrow;          // swizzled SOURCE granule
    // B read offsets (bytes) into Bb[buf]: row = hd01*64+q*16+m, phys granule
    const int gphys = ((jhalf * 4 + kg) ^ (m & 7)) * 16;
    const int boff0 = (hd01 * 64 +  0 + m) * 128 + gphys;
    const int boff1 = (hd01 * 64 + 16 + m) * 128 + gphys;
    const int boff2 = (hd01 * 64 + 32 + m) * 128 + gphys;
    const int boff3 = (hd01 * 64 + 48 + m) * 128 + gphys;

#define STAGE(buf, jt) {                                                                 \
    const unsigned short* s0 = WhT + (size_t)(hdbase * 64 + wv * 8 + lrow) * NN          \
                               + (jt) * 64 + sgr * 8;                                    \
    gl16(s0, &Bb[buf][(wv * 8 + lrow) * 64 + (lane & 7) * 8]);                           \
    gl16(s0 + (size_t)64 * NN, &Bb[buf][(64 + wv * 8 + lrow) * 64 + (lane & 7) * 8]);    \
    if (wv < 2) gl4(rightT + (hdbase + wv) * NN + (jt) * 64 + lane, &rb[buf][wv][lane]); \
}

    f32x4 acc0 = (f32x4){0,0,0,0}, acc1 = acc0, acc2 = acc0, acc3 = acc0;
    float lpart = 0.f;
    const int mrow_off = (rh * 16 + m) * 132;

    STAGE(0, 0);
    __syncthreads();

    for (int jt = 0; jt < 64; ++jt) {
        const int cur = jt & 1;
        if (jt < 63) STAGE(cur ^ 1, jt + 1);

        // loads from LDS (issue early; compiler inserts fine-grained lgkmcnt)
        const unsigned mword = mask_lds[mrow_off + jt * 2 + jhalf];
        const float4 ra  = *(const float4*)&rb[cur][hd01][jhalf * 32 + kg * 8];
        const float4 rb4 = *(const float4*)&rb[cur][hd01][jhalf * 32 + kg * 8 + 4];
        union { uint4 u; bf16x8 v; } B0, B1, B2, B3;
        const char* bbase = (const char*)&Bb[cur][0];
        B0.u = *(const uint4*)(bbase + boff0);
        B1.u = *(const uint4*)(bbase + boff1);
        B2.u = *(const uint4*)(bbase + boff2);
        B3.u = *(const uint4*)(bbase + boff3);

        const unsigned aw = mword >> (kg * 8);
        const float rv[8] = { ra.x, ra.y, ra.z, ra.w, rb4.x, rb4.y, rb4.z, rb4.w };
        union { __bf16 b[8]; bf16x8 v; } Af;
#pragma unroll
        for (int i = 0; i < 8; ++i) {
            const float p = rv[i] + lf2;
            const float q = fmaf(p, ALPHA, qc);
            const float t = fmaxf(p, q);
            float w = exp2f(t);
            const unsigned mk = (unsigned)(((int)(aw << (31 - i))) >> 31);
            w = __uint_as_float(__float_as_uint(w) & mk);
            lpart += w;
            Af.b[i] = (__bf16)w;
        }
        acc0 = __builtin_amdgcn_mfma_f32_16x16x32_bf16(Af.v, B0.v, acc0, 0, 0, 0);
        acc1 = __builtin_amdgcn_mfma_f32_16x16x32_bf16(Af.v, B1.v, acc1, 0, 0, 0);
        acc2 = __builtin_amdgcn_mfma_f32_16x16x32_bf16(Af.v, B2.v, acc2, 0, 0, 0);
        acc3 = __builtin_amdgcn_mfma_f32_16x16x32_bf16(Af.v, B3.v, acc3, 0, 0, 0);

        __syncthreads();   // drains STAGE vmcnt + protects buffer swap
    }
#undef STAGE

    const int grp = rh * 2 + hd01;
    if (jhalf == 1) {
#pragma unroll
        for (int i = 0; i < 4; ++i) {
            comb[grp][lane][ 0 + i] = acc0[i];
            comb[grp][lane][ 4 + i] = acc1[i];
            comb[grp][lane][ 8 + i] = acc2[i];
            comb[grp][lane][12 + i] = acc3[i];
        }
        comb[grp][lane][16] = lpart;
    }
    __syncthreads();
    if (jhalf == 0) {
#pragma unroll
        for (int i = 0; i < 4; ++i) {
            acc0[i] += comb[grp][lane][ 0 + i];
            acc1[i] += comb[grp][lane][ 4 + i];
            acc2[i] += comb[grp][lane][ 8 + i];
            acc3[i] += comb[grp][lane][12 + i];
        }
        lpart += comb[grp][lane][16];
        float lsum = lpart;
        lsum += __shfl_xor(lsum, 16, 64);
        lsum += __shfl_xor(lsum, 32, 64);   // full denom for row m on every lane

#pragma unroll
        for (int q = 0; q < 4; ++q) {
            const f32x4 A = (q == 0) ? acc0 : (q == 1) ? acc1 : (q == 2) ? acc2 : acc3;
            const int col = hd * 64 + q * 16 + m;
            const float bv = bias[col];
#pragma unroll
            for (int i = 0; i < 4; ++i) {
                const int r = kg * 4 + i;
                const float lr = __shfl(lsum, r, 64);
                out[(size_t)(rowbase + rh * 16 + r) * C_TOT + col] = A[i] / lr + bv;
            }
        }
    }
}

extern "C" void kernel_launch(void* const* d_in, const int* in_sizes, int n_in,
                              void* d_out, int out_size, void* d_ws, size_t ws_size,
                              hipStream_t stream) {
    const float* hmat = (const float*)d_in[0];
    const int*   adj  = (const int*)d_in[1];
    const float* W    = (const float*)d_in[2];
    const float* a    = (const float*)d_in[3];
    const float* bias = (const float*)d_in[4];
    float* out = (float*)d_out;

    char* ws = (char*)d_ws;
    unsigned short* WhT  = (unsigned short*)(ws + 0x000000);  // 2MB
    float* rightT        = (float*)(ws + 0x280000);           // 64KB
    float* leftT         = (float*)(ws + 0x2A0000);           // 64KB
    unsigned short* WTbf = (unsigned short*)(ws + 0x2B0000);  // 64KB
    float* uLR           = (float*)(ws + 0x2C0000);           // 4KB
    unsigned int* Rmax   = (unsigned int*)(ws + 0x2C1000);    // 16B
    unsigned* mask       = (unsigned*)(ws + 0x300000);        // 2MB

    hipLaunchKernelGGL(k_misc, dim3(32),   dim3(256), 0, stream, W, a, WTbf, uLR, Rmax);
    hipLaunchKernelGGL(k_mask, dim3(1024), dim3(256), 0, stream, adj, mask);
    hipLaunchKernelGGL(k_prep, dim3(256),  dim3(256), 0, stream, hmat, WTbf, uLR, WhT, leftT, rightT, Rmax);
    hipLaunchKernelGGL(k_attn, dim3(256),  dim3(512), 0, stream, mask, WhT, leftT, rightT, Rmax, bias, out);
}

// Round 9
// 72.361 us; speedup vs baseline: 1.9953x; 1.3652x over previous
//
#include <hip/hip_runtime.h>
#include <hip/hip_bf16.h>

#define NN 4096
#define IN_F 128
#define OUT_F 64
#define C_TOT 256
#define ALPHA 0.2f
#define LOG2E 1.4426950408889634f

typedef float f32x4 __attribute__((ext_vector_type(4)));
typedef __bf16 bf16x8 __attribute__((ext_vector_type(8)));

__device__ __forceinline__ unsigned fmap(float f) {
    unsigned u = __float_as_uint(f);
    return (u >> 31) ? ~u : (u | 0x80000000u);
}
__device__ __forceinline__ float funmap(unsigned u) {
    return (u >> 31) ? __uint_as_float(u & 0x7FFFFFFFu) : __uint_as_float(~u);
}
__device__ __forceinline__ unsigned short bfbits(float x) {
    union { __bf16 b; unsigned short u; } t;
    t.b = (__bf16)x;
    return t.u;
}
__device__ __forceinline__ void gl16(const void* g, void* l) {
    __builtin_amdgcn_global_load_lds((const __attribute__((address_space(1))) void*)g,
                                     (__attribute__((address_space(3))) void*)l, 16, 0, 0);
}

// ---------------------------------------------------------------------------
// K0: WT bf16 [256][128], u = per-head W@a ([128][8]), zero Rmax. Grid 32x256.
// ---------------------------------------------------------------------------
__global__ __launch_bounds__(256) void k_misc(
    const float* __restrict__ W, const float* __restrict__ a,
    unsigned short* __restrict__ WTbf, float* __restrict__ uLR,
    unsigned int* __restrict__ Rmax)
{
    const int b = blockIdx.x, tid = threadIdx.x;
    const int c = b * 8 + (tid & 7);
#pragma unroll
    for (int pass = 0; pass < 4; ++pass) {
        const int k = pass * 32 + (tid >> 3);
        WTbf[(size_t)c * IN_F + k] = bfbits(W[k * C_TOT + c]);
    }
    if (b == 0) {
        if (tid < 4) Rmax[tid] = 0u;
        for (int o = tid; o < 1024; o += 256) {
            const int k = o >> 3, j = o & 7;
            const int hd = j & 3, side = j >> 2;
            float s = 0.f;
            for (int f = 0; f < OUT_F; ++f)
                s = fmaf(W[k * C_TOT + hd * OUT_F + f], a[side * OUT_F + f], s);
            uLR[k * 8 + side * 4 + hd] = s;
        }
    }
}

// ---------------------------------------------------------------------------
// K1: adj (int32 0/1, 64MB) -> bitmask [4096][128 words] (2MB) via ballot.
// ---------------------------------------------------------------------------
__global__ __launch_bounds__(256) void k_mask(
    const int* __restrict__ adj, unsigned* __restrict__ mask)
{
    const int lane = threadIdx.x & 63, wv = threadIdx.x >> 6;
    const int row = blockIdx.x * 4 + wv;
    const int* __restrict__ ar = adj + (size_t)row * NN;
    unsigned* __restrict__ mr = mask + (size_t)row * 128;
    for (int c = 0; c < 8; ++c) {
        const int j0 = c * 512;
        unsigned w = 0u;
#pragma unroll
        for (int k = 0; k < 8; ++k) {
            const unsigned long long bb = __ballot(ar[j0 + k * 64 + lane] > 0);
            const unsigned lo = (unsigned)bb, hi = (unsigned)(bb >> 32);
            if ((lane >> 1) == k) w = (lane & 1) ? hi : lo;
        }
        if (lane < 16) mr[(j0 >> 5) + lane] = w;
    }
}

// ---------------------------------------------------------------------------
// K2: Wh via MFMA -> WhT [256][4096] bf16; f32 left / right*LOG2E; Rmax atomic.
// ---------------------------------------------------------------------------
__global__ __launch_bounds__(256) void k_prep(
    const float* __restrict__ hmat, const unsigned short* __restrict__ WTbf,
    const float* __restrict__ uLR, unsigned short* __restrict__ WhT,
    float* __restrict__ leftT, float* __restrict__ rightT,
    unsigned int* __restrict__ Rmax)
{
    __shared__ float hs[16][132];
    __shared__ float us[128][8];
    const int tid = threadIdx.x;
    const int rowbase = blockIdx.x * 16;

    ((float4*)us)[tid] = ((const float4*)uLR)[tid];
#pragma unroll
    for (int p = 0; p < 8; ++p) {
        const int idx = p * 256 + tid;
        hs[idx >> 7][idx & 127] = hmat[(size_t)rowbase * IN_F + idx];
    }
    __syncthreads();

    const int lane = tid & 63, wv = tid >> 6;
    const int m16 = lane & 15, kg = lane >> 4;

    if (wv == 0) {
        const int row = lane >> 2, hd = lane & 3;
        float aL = 0.f, aR = 0.f;
#pragma unroll
        for (int k = 0; k < 128; k += 4) {
            const float4 hv = *(const float4*)&hs[row][k];
            aL = fmaf(hv.x, us[k][hd],   fmaf(hv.y, us[k+1][hd],   fmaf(hv.z, us[k+2][hd],   fmaf(hv.w, us[k+3][hd],   aL))));
            aR = fmaf(hv.x, us[k][hd+4], fmaf(hv.y, us[k+1][hd+4], fmaf(hv.z, us[k+2][hd+4], fmaf(hv.w, us[k+3][hd+4], aR))));
        }
        leftT [hd * NN + rowbase + row] = aL;
        rightT[hd * NN + rowbase + row] = aR * LOG2E;
        float mx = aR;
#pragma unroll
        for (int s = 4; s < 64; s <<= 1) mx = fmaxf(mx, __shfl_xor(mx, s, 64));
        if (lane < 4) atomicMax(&Rmax[hd], fmap(mx));
    }

    bf16x8 afr[4];
#pragma unroll
    for (int ks = 0; ks < 4; ++ks) {
        const float4 lo = *(const float4*)&hs[m16][ks * 32 + kg * 8];
        const float4 hi = *(const float4*)&hs[m16][ks * 32 + kg * 8 + 4];
        bf16x8 v;
        v[0] = (__bf16)lo.x; v[1] = (__bf16)lo.y; v[2] = (__bf16)lo.z; v[3] = (__bf16)lo.w;
        v[4] = (__bf16)hi.x; v[5] = (__bf16)hi.y; v[6] = (__bf16)hi.z; v[7] = (__bf16)hi.w;
        afr[ks] = v;
    }

#pragma unroll
    for (int nt0 = 0; nt0 < 4; ++nt0) {
        const int col = (wv * 4 + nt0) * 16 + m16;
        f32x4 acc = (f32x4){0.f, 0.f, 0.f, 0.f};
#pragma unroll
        for (int ks = 0; ks < 4; ++ks) {
            union { uint4 u; bf16x8 v; } B;
            B.u = *(const uint4*)(WTbf + (size_t)col * IN_F + ks * 32 + kg * 8);
            acc = __builtin_amdgcn_mfma_f32_16x16x32_bf16(afr[ks], B.v, acc, 0, 0, 0);
        }
#pragma unroll
        for (int i = 0; i < 4; ++i)
            WhT[(size_t)col * NN + rowbase + kg * 4 + i] = bfbits(acc[i]);
    }
}

// ---------------------------------------------------------------------------
// K3: attention + PV. Grid 512 x 512 (block = 32 rows x 1 head; 2 blocks/CU).
// 8 waves = rowhalf(2) x j-quarter(4); j-tile 128. B panel (64 x 128 bf16,
// 16KB) double-buffered via global_load_lds (NO dest registers -> no asm-load
// register hazards), counted s_waitcnt vmcnt(2) + raw s_barrier so prefetch
// stays in flight ACROSS the barrier (T3+T4). XOR-swizzled B (T2, rule 21:
// linear dest + inverse-swizzled source + swizzled read). mask + rightT
// preloaded to LDS once; comb overlays the B buffers (barrier-separated).
// ---------------------------------------------------------------------------
__global__ __launch_bounds__(512, 4) void k_attn(
    const unsigned* __restrict__ mask,
    const unsigned short* __restrict__ WhT,
    const float* __restrict__ leftT,
    const float* __restrict__ rightT,   // pre-scaled by LOG2E
    const unsigned int* __restrict__ Rmax,
    const float* __restrict__ bias,
    float* __restrict__ out)
{
    __shared__ unsigned short Bb[2][64 * 128];   // 2 x 16KB (comb overlays)
    __shared__ float rlds[4096];                 // 16KB: this head's rightT
    __shared__ unsigned mask_lds[32 * 132];      // 16.5KB: 32 rows

    const int tid = threadIdx.x;
    const int lane = tid & 63;
    const int wv = tid >> 6;        // 0..7
    const int rh = wv & 1;          // row half
    const int j4 = wv >> 1;         // 0..3: 32-col quarter of the 128-col tile
    const int rowbase = (blockIdx.x >> 2) * 32;
    const int hd = blockIdx.x & 3;
    const int m = lane & 15;
    const int kg = lane >> 4;
    const int sh = kg * 8;

    // ---- one-time preloads (compiler loads; drained by __syncthreads) ----
#pragma unroll
    for (int p = 0; p < 2; ++p) {
        const int i = p * 512 + tid;   // uint4 index 0..1023 (32 rows x 32)
        const uint4 v = *(const uint4*)(mask + (size_t)(rowbase + (i >> 5)) * 128 + (i & 31) * 4);
        *(uint4*)&mask_lds[(i >> 5) * 132 + (i & 31) * 4] = v;
    }
#pragma unroll
    for (int p = 0; p < 2; ++p) {
        const int i = p * 512 + tid;   // float4 index 0..1023
        *(float4*)&rlds[i * 4] = *(const float4*)(rightT + (size_t)hd * NN + i * 4);
    }

    // softmax constants (global right-max upper bound)
    const float lf = leftT[hd * NN + rowbase + rh * 16 + m];
    const float rmx = funmap(Rmax[hd]);
    const float x = lf + rmx;
    const float m0v = fmaxf(x, ALPHA * x);
    const float mp0 = m0v * LOG2E;
    const float lf2 = fmaf(lf, LOG2E, -mp0);
    const float qc = -0.8f * mp0;

    __syncthreads();

    // ---- staging geometry: 64 rows x 16 granules (16B), 2 issues/thread ----
    const int srow0 = wv * 4 + (lane >> 4);        // 0..31 (issue 1: +32)
    const int g_lin = lane & 15;                   // linear dest granule
    const int lg = g_lin ^ (srow0 & 15);           // inverse-swizzled source
    const unsigned short* gsrc0 = WhT + (size_t)(hd * 64 + srow0) * NN + lg * 8;
    const unsigned short* gsrc1 = gsrc0 + (size_t)32 * NN;  // (srow0+32)&15 == srow0&15
    const int d0 = wv * 512 + lane * 8;            // short idx (== uniform + lane*16B)

#define STAGE(buf, t) {                                  \
    gl16(gsrc0 + (t) * 128, &Bb[buf][d0]);               \
    gl16(gsrc1 + (t) * 128, &Bb[buf][4096 + d0]); }

    // B read offsets (shorts): row q*16+m, physical granule (j4*4+kg)^m
    const int pg8 = ((j4 * 4 + kg) ^ m) * 8;
    const int bro = m * 128 + pg8;                 // + q*2048

    f32x4 acc0 = (f32x4){0,0,0,0}, acc1 = acc0, acc2 = acc0, acc3 = acc0;
    float lpart = 0.f;
    const int mrow_off = (rh * 16 + m) * 132;

#define COMPUTE(buf, t) {                                                        \
    const unsigned aw = mask_lds[mrow_off + (t) * 4 + j4] >> sh;                 \
    const float4 ra  = *(const float4*)&rlds[(t) * 128 + j4 * 32 + sh];          \
    const float4 rb4 = *(const float4*)&rlds[(t) * 128 + j4 * 32 + sh + 4];      \
    const float rv[8] = { ra.x, ra.y, ra.z, ra.w, rb4.x, rb4.y, rb4.z, rb4.w };  \
    union { __bf16 b[8]; bf16x8 v; } Af;                                         \
    _Pragma("unroll")                                                            \
    for (int i = 0; i < 8; ++i) {                                                \
        const float p = rv[i] + lf2;                                             \
        const float q = fmaf(p, ALPHA, qc);                                      \
        const float t2 = fmaxf(p, q);                                            \
        float w = exp2f(t2);                                                     \
        const unsigned mk = (unsigned)(((int)(aw << (31 - i))) >> 31);           \
        w = __uint_as_float(__float_as_uint(w) & mk);                            \
        lpart += w;                                                              \
        Af.b[i] = (__bf16)w;                                                     \
    }                                                                            \
    union { uint4 u; bf16x8 v; } B0, B1, B2, B3;                                 \
    B0.u = *(const uint4*)&Bb[buf][bro];                                         \
    B1.u = *(const uint4*)&Bb[buf][bro + 2048];                                  \
    B2.u = *(const uint4*)&Bb[buf][bro + 4096];                                  \
    B3.u = *(const uint4*)&Bb[buf][bro + 6144];                                  \
    acc0 = __builtin_amdgcn_mfma_f32_16x16x32_bf16(Af.v, B0.v, acc0, 0, 0, 0);   \
    acc1 = __builtin_amdgcn_mfma_f32_16x16x32_bf16(Af.v, B1.v, acc1, 0, 0, 0);   \
    acc2 = __builtin_amdgcn_mfma_f32_16x16x32_bf16(Af.v, B2.v, acc2, 0, 0, 0);   \
    acc3 = __builtin_amdgcn_mfma_f32_16x16x32_bf16(Af.v, B3.v, acc3, 0, 0, 0);   \
}

    STAGE(0, 0);
    for (int t = 0; t < 31; ++t) {
        STAGE((t + 1) & 1, t + 1);                 // prefetch next tile
        asm volatile("s_waitcnt vmcnt(2)" ::: "memory");  // own tile-t DMAs done
        __builtin_amdgcn_sched_barrier(0);
        __builtin_amdgcn_s_barrier();              // everyone's tile-t landed
        COMPUTE(t & 1, t);
        __builtin_amdgcn_sched_barrier(0);
        __builtin_amdgcn_s_barrier();              // all reads done; WAR-safe
    }
    asm volatile("s_waitcnt vmcnt(0)" ::: "memory");
    __builtin_amdgcn_sched_barrier(0);
    __builtin_amdgcn_s_barrier();
    COMPUTE(1, 31);
#undef STAGE
#undef COMPUTE

    // ---- combine across j-quarters; comb overlays Bb (barrier-separated) ----
    __syncthreads();
    float* comb = (float*)&Bb[0][0];               // [3][2][64][17] = 26.1KB
    if (j4 > 0) {
        float* c = comb + (((j4 - 1) * 2 + rh) * 64 + lane) * 17;
#pragma unroll
        for (int i = 0; i < 4; ++i) {
            c[ 0 + i] = acc0[i]; c[ 4 + i] = acc1[i];
            c[ 8 + i] = acc2[i]; c[12 + i] = acc3[i];
        }
        c[16] = lpart;
    }
    __syncthreads();
    if (j4 == 0) {
#pragma unroll
        for (int pt = 0; pt < 3; ++pt) {
            const float* c = comb + ((pt * 2 + rh) * 64 + lane) * 17;
#pragma unroll
            for (int i = 0; i < 4; ++i) {
                acc0[i] += c[ 0 + i]; acc1[i] += c[ 4 + i];
                acc2[i] += c[ 8 + i]; acc3[i] += c[12 + i];
            }
            lpart += c[16];
        }
        float lsum = lpart;
        lsum += __shfl_xor(lsum, 16, 64);
        lsum += __shfl_xor(lsum, 32, 64);   // full row denominator on every lane

#pragma unroll
        for (int q = 0; q < 4; ++q) {
            const f32x4 A = (q == 0) ? acc0 : (q == 1) ? acc1 : (q == 2) ? acc2 : acc3;
            const int col = hd * 64 + q * 16 + m;
            const float bv = bias[col];
#pragma unroll
            for (int i = 0; i < 4; ++i) {
                const int r = kg * 4 + i;
                const float lr = __shfl(lsum, r, 64);
                out[(size_t)(rowbase + rh * 16 + r) * C_TOT + col] = A[i] / lr + bv;
            }
        }
    }
}

extern "C" void kernel_launch(void* const* d_in, const int* in_sizes, int n_in,
                              void* d_out, int out_size, void* d_ws, size_t ws_size,
                              hipStream_t stream) {
    const float* hmat = (const float*)d_in[0];
    const int*   adj  = (const int*)d_in[1];
    const float* W    = (const float*)d_in[2];
    const float* a    = (const float*)d_in[3];
    const float* bias = (const float*)d_in[4];
    float* out = (float*)d_out;

    char* ws = (char*)d_ws;
    unsigned short* WhT  = (unsigned short*)(ws + 0x000000);  // 2MB + pad
    float* rightT        = (float*)(ws + 0x280000);           // 64KB + pad
    float* leftT         = (float*)(ws + 0x2A0000);           // 64KB
    unsigned short* WTbf = (unsigned short*)(ws + 0x2B0000);  // 64KB
    float* uLR           = (float*)(ws + 0x2C0000);           // 4KB
    unsigned int* Rmax   = (unsigned int*)(ws + 0x2C1000);    // 16B
    unsigned* mask       = (unsigned*)(ws + 0x300000);        // 2MB

    hipLaunchKernelGGL(k_misc, dim3(32),   dim3(256), 0, stream, W, a, WTbf, uLR, Rmax);
    hipLaunchKernelGGL(k_mask, dim3(1024), dim3(256), 0, stream, adj, mask);
    hipLaunchKernelGGL(k_prep, dim3(256),  dim3(256), 0, stream, hmat, WTbf, uLR, WhT, leftT, rightT, Rmax);
    hipLaunchKernelGGL(k_attn, dim3(512),  dim3(512), 0, stream, mask, WhT, leftT, rightT, Rmax, bias, out);
}

// Round 10
// 69.242 us; speedup vs baseline: 2.0852x; 1.0450x over previous
//
#include <hip/hip_runtime.h>
#include <hip/hip_bf16.h>

#define NN 4096
#define IN_F 128
#define OUT_F 64
#define C_TOT 256
#define ALPHA 0.2f
#define LOG2E 1.4426950408889634f

typedef float f32x4 __attribute__((ext_vector_type(4)));
typedef __bf16 bf16x8 __attribute__((ext_vector_type(8)));

__device__ __forceinline__ unsigned fmap(float f) {
    unsigned u = __float_as_uint(f);
    return (u >> 31) ? ~u : (u | 0x80000000u);
}
__device__ __forceinline__ float funmap(unsigned u) {
    return (u >> 31) ? __uint_as_float(u & 0x7FFFFFFFu) : __uint_as_float(~u);
}
__device__ __forceinline__ unsigned short bfbits(float x) {
    union { __bf16 b; unsigned short u; } t;
    t.b = (__bf16)x;
    return t.u;
}
__device__ __forceinline__ void gl16(const void* g, void* l) {
    __builtin_amdgcn_global_load_lds((const __attribute__((address_space(1))) void*)g,
                                     (__attribute__((address_space(3))) void*)l, 16, 0, 0);
}

// ---------------------------------------------------------------------------
// K1: adj -> PERMUTED bitmask (word w of row -> pos (w&3)*32 + (w>>2), i.e.
// [j4 quarter][tile]) via ballot. Blocks 0..31 additionally transpose W to
// WTbf bf16 [256][128]; block 0 computes uLR = W@a and zeroes Rmax (merged
// k_misc). Grid 1024 x 256.
// ---------------------------------------------------------------------------
__global__ __launch_bounds__(256) void k_mask(
    const int* __restrict__ adj, unsigned* __restrict__ mask,
    const float* __restrict__ W, const float* __restrict__ a,
    unsigned short* __restrict__ WTbf, float* __restrict__ uLR,
    unsigned int* __restrict__ Rmax)
{
    const int tid = threadIdx.x;
    const int lane = tid & 63, wv = tid >> 6;
    const int row = blockIdx.x * 4 + wv;
    const int* __restrict__ ar = adj + (size_t)row * NN;
    unsigned* __restrict__ mr = mask + (size_t)row * 128;
    for (int c = 0; c < 8; ++c) {
        const int j0 = c * 512;
        unsigned w = 0u;
#pragma unroll
        for (int k = 0; k < 8; ++k) {
            const unsigned long long bb = __ballot(ar[j0 + k * 64 + lane] > 0);
            const unsigned lo = (unsigned)bb, hi = (unsigned)(bb >> 32);
            if ((lane >> 1) == k) w = (lane & 1) ? hi : lo;
        }
        if (lane < 16) {
            const int wi = c * 16 + lane;               // original word index
            mr[(wi & 3) * 32 + (wi >> 2)] = w;          // permuted position
        }
    }

    if (blockIdx.x < 32) {      // merged k_misc
        const int b = blockIdx.x;
        const int c = b * 8 + (tid & 7);
#pragma unroll
        for (int pass = 0; pass < 4; ++pass) {
            const int k = pass * 32 + (tid >> 3);
            WTbf[(size_t)c * IN_F + k] = bfbits(W[k * C_TOT + c]);
        }
        if (b == 0) {
            if (tid < 4) Rmax[tid] = 0u;
            for (int o = tid; o < 1024; o += 256) {
                const int k = o >> 3, j = o & 7;
                const int hd = j & 3, side = j >> 2;
                float s = 0.f;
                for (int f = 0; f < OUT_F; ++f)
                    s = fmaf(W[k * C_TOT + hd * OUT_F + f], a[side * OUT_F + f], s);
                uLR[k * 8 + side * 4 + hd] = s;
            }
        }
    }
}

// ---------------------------------------------------------------------------
// K2: Wh via MFMA -> WhT [256][4096] bf16; f32 left / right*LOG2E; Rmax atomic.
// ---------------------------------------------------------------------------
__global__ __launch_bounds__(256) void k_prep(
    const float* __restrict__ hmat, const unsigned short* __restrict__ WTbf,
    const float* __restrict__ uLR, unsigned short* __restrict__ WhT,
    float* __restrict__ leftT, float* __restrict__ rightT,
    unsigned int* __restrict__ Rmax)
{
    __shared__ float hs[16][132];
    __shared__ float us[128][8];
    const int tid = threadIdx.x;
    const int rowbase = blockIdx.x * 16;

    ((float4*)us)[tid] = ((const float4*)uLR)[tid];
#pragma unroll
    for (int p = 0; p < 8; ++p) {
        const int idx = p * 256 + tid;
        hs[idx >> 7][idx & 127] = hmat[(size_t)rowbase * IN_F + idx];
    }
    __syncthreads();

    const int lane = tid & 63, wv = tid >> 6;
    const int m16 = lane & 15, kg = lane >> 4;

    if (wv == 0) {
        const int row = lane >> 2, hd = lane & 3;
        float aL = 0.f, aR = 0.f;
#pragma unroll
        for (int k = 0; k < 128; k += 4) {
            const float4 hv = *(const float4*)&hs[row][k];
            aL = fmaf(hv.x, us[k][hd],   fmaf(hv.y, us[k+1][hd],   fmaf(hv.z, us[k+2][hd],   fmaf(hv.w, us[k+3][hd],   aL))));
            aR = fmaf(hv.x, us[k][hd+4], fmaf(hv.y, us[k+1][hd+4], fmaf(hv.z, us[k+2][hd+4], fmaf(hv.w, us[k+3][hd+4], aR))));
        }
        leftT [hd * NN + rowbase + row] = aL;
        rightT[hd * NN + rowbase + row] = aR * LOG2E;
        float mx = aR;
#pragma unroll
        for (int s = 4; s < 64; s <<= 1) mx = fmaxf(mx, __shfl_xor(mx, s, 64));
        if (lane < 4) atomicMax(&Rmax[hd], fmap(mx));
    }

    bf16x8 afr[4];
#pragma unroll
    for (int ks = 0; ks < 4; ++ks) {
        const float4 lo = *(const float4*)&hs[m16][ks * 32 + kg * 8];
        const float4 hi = *(const float4*)&hs[m16][ks * 32 + kg * 8 + 4];
        bf16x8 v;
        v[0] = (__bf16)lo.x; v[1] = (__bf16)lo.y; v[2] = (__bf16)lo.z; v[3] = (__bf16)lo.w;
        v[4] = (__bf16)hi.x; v[5] = (__bf16)hi.y; v[6] = (__bf16)hi.z; v[7] = (__bf16)hi.w;
        afr[ks] = v;
    }

#pragma unroll
    for (int nt0 = 0; nt0 < 4; ++nt0) {
        const int col = (wv * 4 + nt0) * 16 + m16;
        f32x4 acc = (f32x4){0.f, 0.f, 0.f, 0.f};
#pragma unroll
        for (int ks = 0; ks < 4; ++ks) {
            union { uint4 u; bf16x8 v; } B;
            B.u = *(const uint4*)(WTbf + (size_t)col * IN_F + ks * 32 + kg * 8);
            acc = __builtin_amdgcn_mfma_f32_16x16x32_bf16(afr[ks], B.v, acc, 0, 0, 0);
        }
#pragma unroll
        for (int i = 0; i < 4; ++i)
            WhT[(size_t)col * NN + rowbase + kg * 4 + i] = bfbits(acc[i]);
    }
}

// ---------------------------------------------------------------------------
// K3: attention + PV. Grid 512 x 512 (block = 32 rows x 1 head).
// 4-buffer LDS pipeline (64KB) + rightT LDS (16KB) = 80KB -> 2 blocks/CU.
// Depth-2 prefetch via global_load_lds, counted vmcnt(4) steady-state
// (tail 2 -> 0), ONE raw s_barrier per tile (4 buffers make WAR safe at
// skew<=1). Mask held in 32 VGPRs (permuted global layout, full unroll ->
// static indexing). XOR-swizzled B staging (linear dest + inv-swz source).
// ---------------------------------------------------------------------------
__global__ __launch_bounds__(512, 4) void k_attn(
    const unsigned* __restrict__ mask,   // permuted [row][j4][t]
    const unsigned short* __restrict__ WhT,
    const float* __restrict__ leftT,
    const float* __restrict__ rightT,    // pre-scaled by LOG2E
    const unsigned int* __restrict__ Rmax,
    const float* __restrict__ bias,
    float* __restrict__ out)
{
    __shared__ unsigned short Bb[4][64 * 128];   // 64KB (comb overlays)
    __shared__ float rlds[4096];                 // 16KB: this head's rightT

    const int tid = threadIdx.x;
    const int lane = tid & 63;
    const int wv = tid >> 6;        // 0..7
    const int rh = wv & 1;          // row half
    const int j4 = wv >> 1;         // 0..3: 32-col quarter of the 128-col tile
    const int rowbase = (blockIdx.x >> 2) * 32;
    const int hd = blockIdx.x & 3;
    const int m = lane & 15;
    const int kg = lane >> 4;
    const int sh = kg * 8;

    // ---- one-time preloads ----
#pragma unroll
    for (int p = 0; p < 2; ++p) {
        const int i = p * 512 + tid;   // float4 index 0..1023
        *(float4*)&rlds[i * 4] = *(const float4*)(rightT + (size_t)hd * NN + i * 4);
    }
    // mask words for this lane's row+quarter -> 32 VGPRs (static idx via unroll)
    unsigned mreg[32];
    {
        const unsigned* mrow = mask + (size_t)(rowbase + rh * 16 + m) * 128 + j4 * 32;
#pragma unroll
        for (int p = 0; p < 8; ++p) {
            const uint4 v = *(const uint4*)(mrow + p * 4);
            mreg[p * 4 + 0] = v.x; mreg[p * 4 + 1] = v.y;
            mreg[p * 4 + 2] = v.z; mreg[p * 4 + 3] = v.w;
        }
    }

    // softmax constants (global right-max upper bound)
    const float lf = leftT[hd * NN + rowbase + rh * 16 + m];
    const float rmx = funmap(Rmax[hd]);
    const float x = lf + rmx;
    const float m0v = fmaxf(x, ALPHA * x);
    const float mp0 = m0v * LOG2E;
    const float lf2 = fmaf(lf, LOG2E, -mp0);
    const float qc = -0.8f * mp0;

    __syncthreads();   // rlds visible to all waves

    // ---- staging geometry: 64 rows x 16 granules (16B), 2 issues/thread ----
    const int srow0 = wv * 4 + (lane >> 4);        // 0..31 (second issue: +32)
    const int g_lin = lane & 15;                   // linear dest granule
    const int lg = g_lin ^ (srow0 & 15);           // inverse-swizzled source
    const unsigned short* gsrc0 = WhT + (size_t)(hd * 64 + srow0) * NN + lg * 8;
    const unsigned short* gsrc1 = gsrc0 + (size_t)32 * NN;
    const int d0 = wv * 512 + lane * 8;

#define STAGE(buf, t) {                                  \
    gl16(gsrc0 + (t) * 128, &Bb[buf][d0]);               \
    gl16(gsrc1 + (t) * 128, &Bb[buf][4096 + d0]); }

    // B read offsets (shorts): row q*16+m, physical granule (j4*4+kg)^m
    const int pg8 = ((j4 * 4 + kg) ^ m) * 8;
    const int bro = m * 128 + pg8;                 // + q*2048

    f32x4 acc0 = (f32x4){0,0,0,0}, acc1 = acc0, acc2 = acc0, acc3 = acc0;
    float lpart = 0.f;

#define COMPUTE(buf, t) {                                                        \
    const unsigned aw = mreg[(t)] >> sh;                                         \
    const float4 ra  = *(const float4*)&rlds[(t) * 128 + j4 * 32 + sh];          \
    const float4 rb4 = *(const float4*)&rlds[(t) * 128 + j4 * 32 + sh + 4];      \
    const float rv[8] = { ra.x, ra.y, ra.z, ra.w, rb4.x, rb4.y, rb4.z, rb4.w };  \
    union { __bf16 b[8]; bf16x8 v; } Af;                                         \
    _Pragma("unroll")                                                            \
    for (int i = 0; i < 8; ++i) {                                                \
        const float p = rv[i] + lf2;                                             \
        const float q = fmaf(p, ALPHA, qc);                                      \
        const float t2 = fmaxf(p, q);                                            \
        float w = exp2f(t2);                                                     \
        const unsigned mk = (unsigned)(((int)(aw << (31 - i))) >> 31);           \
        w = __uint_as_float(__float_as_uint(w) & mk);                            \
        lpart += w;                                                              \
        Af.b[i] = (__bf16)w;                                                     \
    }                                                                            \
    union { uint4 u; bf16x8 v; } B0, B1, B2, B3;                                 \
    B0.u = *(const uint4*)&Bb[buf][bro];                                         \
    B1.u = *(const uint4*)&Bb[buf][bro + 2048];                                  \
    B2.u = *(const uint4*)&Bb[buf][bro + 4096];                                  \
    B3.u = *(const uint4*)&Bb[buf][bro + 6144];                                  \
    acc0 = __builtin_amdgcn_mfma_f32_16x16x32_bf16(Af.v, B0.v, acc0, 0, 0, 0);   \
    acc1 = __builtin_amdgcn_mfma_f32_16x16x32_bf16(Af.v, B1.v, acc1, 0, 0, 0);   \
    acc2 = __builtin_amdgcn_mfma_f32_16x16x32_bf16(Af.v, B2.v, acc2, 0, 0, 0);   \
    acc3 = __builtin_amdgcn_mfma_f32_16x16x32_bf16(Af.v, B3.v, acc3, 0, 0, 0);   \
}

    STAGE(0, 0);
    STAGE(1, 1);
#pragma unroll
    for (int t = 0; t < 32; ++t) {
        if (t + 2 < 32) STAGE((t + 2) & 3, t + 2);
        if (t < 30)       { asm volatile("s_waitcnt vmcnt(4)" ::: "memory"); }
        else if (t == 30) { asm volatile("s_waitcnt vmcnt(2)" ::: "memory"); }
        else              { asm volatile("s_waitcnt vmcnt(0)" ::: "memory"); }
        __builtin_amdgcn_sched_barrier(0);
        __builtin_amdgcn_s_barrier();              // everyone's tile-t landed
        __builtin_amdgcn_sched_barrier(0);
        COMPUTE(t & 3, t);
    }
#undef STAGE
#undef COMPUTE

    // ---- combine across j-quarters; comb overlays Bb (barrier-separated) ----
    __syncthreads();
    float* comb = (float*)&Bb[0][0];               // [3][2][64][17] = 26.1KB
    if (j4 > 0) {
        float* c = comb + (((j4 - 1) * 2 + rh) * 64 + lane) * 17;
#pragma unroll
        for (int i = 0; i < 4; ++i) {
            c[ 0 + i] = acc0[i]; c[ 4 + i] = acc1[i];
            c[ 8 + i] = acc2[i]; c[12 + i] = acc3[i];
        }
        c[16] = lpart;
    }
    __syncthreads();
    if (j4 == 0) {
#pragma unroll
        for (int pt = 0; pt < 3; ++pt) {
            const float* c = comb + ((pt * 2 + rh) * 64 + lane) * 17;
#pragma unroll
            for (int i = 0; i < 4; ++i) {
                acc0[i] += c[ 0 + i]; acc1[i] += c[ 4 + i];
                acc2[i] += c[ 8 + i]; acc3[i] += c[12 + i];
            }
            lpart += c[16];
        }
        float lsum = lpart;
        lsum += __shfl_xor(lsum, 16, 64);
        lsum += __shfl_xor(lsum, 32, 64);   // full row denominator on every lane

#pragma unroll
        for (int q = 0; q < 4; ++q) {
            const f32x4 A = (q == 0) ? acc0 : (q == 1) ? acc1 : (q == 2) ? acc2 : acc3;
            const int col = hd * 64 + q * 16 + m;
            const float bv = bias[col];
#pragma unroll
            for (int i = 0; i < 4; ++i) {
                const int r = kg * 4 + i;
                const float lr = __shfl(lsum, r, 64);
                out[(size_t)(rowbase + rh * 16 + r) * C_TOT + col] = A[i] / lr + bv;
            }
        }
    }
}

extern "C" void kernel_launch(void* const* d_in, const int* in_sizes, int n_in,
                              void* d_out, int out_size, void* d_ws, size_t ws_size,
                              hipStream_t stream) {
    const float* hmat = (const float*)d_in[0];
    const int*   adj  = (const int*)d_in[1];
    const float* W    = (const float*)d_in[2];
    const float* a    = (const float*)d_in[3];
    const float* bias = (const float*)d_in[4];
    float* out = (float*)d_out;

    char* ws = (char*)d_ws;
    unsigned short* WhT  = (unsigned short*)(ws + 0x000000);  // 2MB + pad
    float* rightT        = (float*)(ws + 0x280000);           // 64KB + pad
    float* leftT         = (float*)(ws + 0x2A0000);           // 64KB
    unsigned short* WTbf = (unsigned short*)(ws + 0x2B0000);  // 64KB
    float* uLR           = (float*)(ws + 0x2C0000);           // 4KB
    unsigned int* Rmax   = (unsigned int*)(ws + 0x2C1000);    // 16B
    unsigned* mask       = (unsigned*)(ws + 0x300000);        // 2MB

    hipLaunchKernelGGL(k_mask, dim3(1024), dim3(256), 0, stream,
                       adj, mask, W, a, WTbf, uLR, Rmax);
    hipLaunchKernelGGL(k_prep, dim3(256),  dim3(256), 0, stream,
                       hmat, WTbf, uLR, WhT, leftT, rightT, Rmax);
    hipLaunchKernelGGL(k_attn, dim3(512),  dim3(512), 0, stream,
                       mask, WhT, leftT, rightT, Rmax, bias, out);
}